// Round 1
// baseline (159.517 us; speedup 1.0000x reference)
//
#include <hip/hip_runtime.h>

// Problem constants (from reference)
#define BATCH 2048
#define FDIM  1024
#define GTILE 16
#define F4    (FDIM / 4)          // 256 float4 per row
#define CHUNKS 32
#define ROWS_PER_CHUNK (BATCH / CHUNKS)  // 64

// ws layout (in floats):
//   p1  : [CHUNKS][FDIM]   partial column sums of xf            @ 0
//   p2s : [CHUNKS][FDIM]   partial column sums of relu(xf-mean) @ 32768
//   p2q : [CHUNKS][FDIM]   partial column sumsq of relu(...)    @ 65536
//   mean: [FDIM]                                                @ 98304
//   sc  : [FDIM]   scale = wp / sd                              @ 99328
//   cc  : [FDIM]   mu * scale                                   @ 100352
#define OFF_P1   0
#define OFF_P2S  32768
#define OFF_P2Q  65536
#define OFF_MEAN 98304
#define OFF_SC   99328
#define OFF_CC   100352

__global__ void k1_partial_sum(const float4* __restrict__ xf, float4* __restrict__ p1) {
    const int tid = threadIdx.x;            // 0..255 -> 4 columns each
    const int chunk = blockIdx.x;           // 0..31
    const float4* p = xf + (size_t)chunk * ROWS_PER_CHUNK * F4 + tid;
    float4 s = {0.f, 0.f, 0.f, 0.f};
#pragma unroll 8
    for (int r = 0; r < ROWS_PER_CHUNK; ++r) {
        float4 v = p[r * F4];
        s.x += v.x; s.y += v.y; s.z += v.z; s.w += v.w;
    }
    p1[chunk * F4 + tid] = s;
}

__global__ void k2_relu_partial(const float4* __restrict__ xf,
                                const float4* __restrict__ p1,
                                float4* __restrict__ p2s,
                                float4* __restrict__ p2q) {
    const int tid = threadIdx.x;
    const int chunk = blockIdx.x;
    // Redundantly reduce p1 -> per-column mean for this thread's 4 columns.
    float4 m = {0.f, 0.f, 0.f, 0.f};
#pragma unroll
    for (int c = 0; c < CHUNKS; ++c) {
        float4 v = p1[c * F4 + tid];
        m.x += v.x; m.y += v.y; m.z += v.z; m.w += v.w;
    }
    const float inv_n = 1.0f / (float)BATCH;
    m.x *= inv_n; m.y *= inv_n; m.z *= inv_n; m.w *= inv_n;

    const float4* p = xf + (size_t)chunk * ROWS_PER_CHUNK * F4 + tid;
    float4 s = {0.f, 0.f, 0.f, 0.f};
    float4 q = {0.f, 0.f, 0.f, 0.f};
#pragma unroll 8
    for (int r = 0; r < ROWS_PER_CHUNK; ++r) {
        float4 v = p[r * F4];
        float rx = fmaxf(v.x - m.x, 0.f);
        float ry = fmaxf(v.y - m.y, 0.f);
        float rz = fmaxf(v.z - m.z, 0.f);
        float rw = fmaxf(v.w - m.w, 0.f);
        s.x += rx; s.y += ry; s.z += rz; s.w += rw;
        q.x += rx * rx; q.y += ry * ry; q.z += rz * rz; q.w += rw * rw;
    }
    p2s[chunk * F4 + tid] = s;
    p2q[chunk * F4 + tid] = q;
}

__global__ void k3_finalize(const float* __restrict__ wp,
                            const float4* __restrict__ p1,
                            const float4* __restrict__ p2s,
                            const float4* __restrict__ p2q,
                            float4* __restrict__ mean,
                            float4* __restrict__ sc,
                            float4* __restrict__ cc) {
    const int tid = threadIdx.x;  // 256 threads, one block
    float4 m = {0.f,0.f,0.f,0.f}, s = {0.f,0.f,0.f,0.f}, q = {0.f,0.f,0.f,0.f};
#pragma unroll
    for (int c = 0; c < CHUNKS; ++c) {
        float4 a = p1[c * F4 + tid];
        float4 b = p2s[c * F4 + tid];
        float4 d = p2q[c * F4 + tid];
        m.x += a.x; m.y += a.y; m.z += a.z; m.w += a.w;
        s.x += b.x; s.y += b.y; s.z += b.z; s.w += b.w;
        q.x += d.x; q.y += d.y; q.z += d.z; q.w += d.w;
    }
    const float inv_n = 1.0f / (float)BATCH;
    const float w = wp[0];
    float4 mn, scale, cmb;
    {
        // per component: mu = s/N; var = (q - s*s/N)/(N-1); sc = w/sqrt(var); cc = mu*sc
        float mu, var;
        mn.x = m.x * inv_n;
        mu = s.x * inv_n; var = (q.x - s.x * mu) / (float)(BATCH - 1);
        scale.x = w * rsqrtf(var); cmb.x = mu * scale.x;
        mn.y = m.y * inv_n;
        mu = s.y * inv_n; var = (q.y - s.y * mu) / (float)(BATCH - 1);
        scale.y = w * rsqrtf(var); cmb.y = mu * scale.y;
        mn.z = m.z * inv_n;
        mu = s.z * inv_n; var = (q.z - s.z * mu) / (float)(BATCH - 1);
        scale.z = w * rsqrtf(var); cmb.z = mu * scale.z;
        mn.w = m.w * inv_n;
        mu = s.w * inv_n; var = (q.w - s.w * mu) / (float)(BATCH - 1);
        scale.w = w * rsqrtf(var); cmb.w = mu * scale.w;
    }
    mean[tid] = mn;
    sc[tid]   = scale;
    cc[tid]   = cmb;
}

__global__ void k4_write(const float4* __restrict__ xf,
                         const float4* __restrict__ mean,
                         const float4* __restrict__ sc,
                         const float4* __restrict__ cc,
                         float4* __restrict__ out) {
    const int tid = threadIdx.x;     // 0..255
    const int row = blockIdx.x;      // 0..2047
    float4 m = mean[tid];
    float4 a = sc[tid];
    float4 c = cc[tid];
    float4 v = xf[(size_t)row * F4 + tid];
    float4 o;
    o.x = fmaxf(v.x - m.x, 0.f) * a.x - c.x;
    o.y = fmaxf(v.y - m.y, 0.f) * a.y - c.y;
    o.z = fmaxf(v.z - m.z, 0.f) * a.z - c.z;
    o.w = fmaxf(v.w - m.w, 0.f) * a.w - c.w;
    float4* dst = out + (size_t)row * (GTILE * F4) + tid;
#pragma unroll
    for (int g = 0; g < GTILE; ++g) {
        dst[g * F4] = o;
    }
}

extern "C" void kernel_launch(void* const* d_in, const int* in_sizes, int n_in,
                              void* d_out, int out_size, void* d_ws, size_t ws_size,
                              hipStream_t stream) {
    const float* xf = (const float*)d_in[0];
    const float* wp = (const float*)d_in[1];
    float* ws = (float*)d_ws;
    float* out = (float*)d_out;

    const float4* xf4 = (const float4*)xf;
    float4* p1  = (float4*)(ws + OFF_P1);
    float4* p2s = (float4*)(ws + OFF_P2S);
    float4* p2q = (float4*)(ws + OFF_P2Q);
    float4* mean = (float4*)(ws + OFF_MEAN);
    float4* sc   = (float4*)(ws + OFF_SC);
    float4* cc   = (float4*)(ws + OFF_CC);

    k1_partial_sum<<<CHUNKS, 256, 0, stream>>>(xf4, p1);
    k2_relu_partial<<<CHUNKS, 256, 0, stream>>>(xf4, p1, p2s, p2q);
    k3_finalize<<<1, 256, 0, stream>>>(wp, p1, p2s, p2q, mean, sc, cc);
    k4_write<<<BATCH, 256, 0, stream>>>(xf4, mean, sc, cc, (float4*)out);
}